// Round 9
// baseline (381.655 us; speedup 1.0000x reference)
//
#include <hip/hip_runtime.h>

#define N_NODES  50000
#define N_EDGES  800000
#define HIDDEN   128
#define N_GRAPHS 256
#define N_CLASSES 10
#define WLD 136   // padded LDS leading dim for W tiles (4-bank shift/row -> 2-way max, free)
#define ZLD 136   // padded LDS leading dim for z tile

typedef short short8 __attribute__((ext_vector_type(8)));
typedef float floatx4 __attribute__((ext_vector_type(4)));

__device__ inline unsigned short bf16_rtne(float x) {
    unsigned u = __float_as_uint(x);
    unsigned r = ((u >> 16) & 1u) + 0x7fffu;
    return (unsigned short)((u + r) >> 16);
}

__device__ inline void bf16_split(float a, unsigned short& hi, unsigned short& lo) {
    unsigned u = __float_as_uint(a);
    hi = (unsigned short)(u >> 16);
    float res = a - __uint_as_float(u & 0xffff0000u);
    lo = (unsigned short)(__float_as_uint(res) >> 16);
}

// ---------------- fused prep: count_pos (blocks 0..3124) | wsplit (3125..3252) | xconv (3253..6377) ----------------
__global__ void prep_kernel(const int* __restrict__ dst, int* __restrict__ deg, int* __restrict__ epos,
                            const float* __restrict__ W1, unsigned short* __restrict__ W1h,
                            unsigned short* __restrict__ W1l,
                            const float* __restrict__ W2, unsigned short* __restrict__ W2h,
                            unsigned short* __restrict__ W2l,
                            const float4* __restrict__ X, uint4* __restrict__ Xb,
                            int* __restrict__ counter) {
    int b = blockIdx.x;
    if (b < 3125) {                              // count_pos: 3125*256 == 800000 exact
        int e = b * 256 + threadIdx.x;
        epos[e] = atomicAdd(&deg[dst[e]], 1);
    } else if (b < 3253) {                       // wsplit: 128*256 == 32768 exact
        int idx = (b - 3125) * 256 + threadIdx.x;
        if (idx == 0) counter[0] = 0;
        int which = idx >> 14, sub = idx & (HIDDEN * HIDDEN - 1);
        int k = sub >> 7, n = sub & 127;
        unsigned short hi, lo;
        bf16_split((which ? W2 : W1)[sub], hi, lo);
        (which ? W2h : W1h)[n * HIDDEN + k] = hi;
        (which ? W2l : W1l)[n * HIDDEN + k] = lo;
    } else {                                     // xconv: 3125*256 == 50000*16 exact
        int i = (b - 3253) * 256 + threadIdx.x;
        int n = i >> 4, c = i & 15;
        float4 a = X[(size_t)n * 32 + c * 2], v = X[(size_t)n * 32 + c * 2 + 1];
        uint4 o;
        o.x = (unsigned)bf16_rtne(a.x) | ((unsigned)bf16_rtne(a.y) << 16);
        o.y = (unsigned)bf16_rtne(a.z) | ((unsigned)bf16_rtne(a.w) << 16);
        o.z = (unsigned)bf16_rtne(v.x) | ((unsigned)bf16_rtne(v.y) << 16);
        o.w = (unsigned)bf16_rtne(v.z) | ((unsigned)bf16_rtne(v.w) << 16);
        Xb[(size_t)(c >> 2) * N_NODES * 4 + (size_t)n * 4 + (c & 3)] = o;
    }
}

__global__ void offsets_kernel(const int* __restrict__ deg, int* __restrict__ row_start,
                               int* __restrict__ counter) {
    int n = blockIdx.x * blockDim.x + threadIdx.x;
    int d = (n < N_NODES) ? deg[n] : 0;
    int lane = threadIdx.x & 63;
    int incl = d;
    #pragma unroll
    for (int off = 1; off < 64; off <<= 1) {
        int v = __shfl_up(incl, off, 64);
        if (lane >= off) incl += v;
    }
    int excl = incl - d;
    int total = __shfl(incl, 63, 64);
    int base = 0;
    if (lane == 0) base = atomicAdd(counter, total);
    base = __shfl(base, 0, 64);
    if (n < N_NODES) row_start[n] = base + excl;
}

__global__ void place_kernel(const int* __restrict__ src, const int* __restrict__ dst,
                             const int* __restrict__ epos, const int* __restrict__ row_start,
                             int* __restrict__ csr_src) {
    int e = blockIdx.x * blockDim.x + threadIdx.x;
    if (e >= N_EDGES) return;
    csr_src[row_start[dst[e]] + epos[e]] = src[e];
}

// ---------------- aggregation, XCD-sliced, sequential per-lane (R8-proven) ----------------
__device__ inline void acc_bf2(unsigned d, float& f0, float& f1) {
    f0 += __uint_as_float(d << 16);
    f1 += __uint_as_float(d & 0xffff0000u);
}
__device__ inline void acc8(const uint4 v, float* a) {
    acc_bf2(v.x, a[0], a[1]); acc_bf2(v.y, a[2], a[3]);
    acc_bf2(v.z, a[4], a[5]); acc_bf2(v.w, a[6], a[7]);
}

__global__ void agg_kernel(const uint4* __restrict__ Xb, const int* __restrict__ row_start,
                           const int* __restrict__ deg, const int* __restrict__ csr_src,
                           uint4* __restrict__ Tb /* row-major bf16 out */) {
    int s = blockIdx.x & 3;
    int n = (blockIdx.x >> 2) * 64 + (threadIdx.x >> 2);
    int chunk = threadIdx.x & 3;
    if (n >= N_NODES) return;
    const uint4* Ts = Xb + (size_t)s * (N_NODES * 4);
    float a[8];
    #pragma unroll
    for (int j = 0; j < 8; ++j) a[j] = 0.f;
    {   // self term
        uint4 v = Ts[(size_t)n * 4 + chunk];
        acc8(v, a);
    }
    int rs = row_start[n], d = deg[n];
    int i = 0;
    for (; i + 4 <= d; i += 4) {
        int s0 = csr_src[rs + i + 0];
        int s1 = csr_src[rs + i + 1];
        int s2 = csr_src[rs + i + 2];
        int s3 = csr_src[rs + i + 3];
        uint4 v0 = Ts[(size_t)s0 * 4 + chunk];
        uint4 v1 = Ts[(size_t)s1 * 4 + chunk];
        uint4 v2 = Ts[(size_t)s2 * 4 + chunk];
        uint4 v3 = Ts[(size_t)s3 * 4 + chunk];
        acc8(v0, a); acc8(v1, a); acc8(v2, a); acc8(v3, a);
    }
    for (; i < d; ++i) {
        int s0 = csr_src[rs + i];
        uint4 v0 = Ts[(size_t)s0 * 4 + chunk];
        acc8(v0, a);
    }
    uint4 o;
    o.x = (unsigned)bf16_rtne(a[0]) | ((unsigned)bf16_rtne(a[1]) << 16);
    o.y = (unsigned)bf16_rtne(a[2]) | ((unsigned)bf16_rtne(a[3]) << 16);
    o.z = (unsigned)bf16_rtne(a[4]) | ((unsigned)bf16_rtne(a[5]) << 16);
    o.w = (unsigned)bf16_rtne(a[6]) | ((unsigned)bf16_rtne(a[7]) << 16);
    Tb[(size_t)n * 16 + s * 4 + chunk] = o;
}

// ---------------- fused MLP: out = act2( relu(T@W1+b1) @ W2 + b2 ) ----------------
// Phase 1 computes z^T = W1T @ T^T: A-frags = staged W1T rows (LDS), B-frags = row-major T
// (global, contiguous k). C-layout gives each lane 4 consecutive z-cols for one node ->
// ds_write_b64 of rtne-bf16 z into row-major LDS tile. Phase 2: normal orientation,
// A-frags = z rows (ds_read_b128), B-frags = W2T (re-staged into same LDS region).
__global__ __launch_bounds__(256, 1)
void mlp_fused(const unsigned short* __restrict__ Ab,
               const unsigned short* __restrict__ W1h, const unsigned short* __restrict__ W1l,
               const float* __restrict__ b1,
               const unsigned short* __restrict__ W2h, const unsigned short* __restrict__ W2l,
               const float* __restrict__ b2,
               unsigned short* __restrict__ Cb, int relu2, int blocked) {
    __shared__ unsigned short WhS[HIDDEN * WLD];   // 34.8 KB (reused W1 -> W2)
    __shared__ unsigned short WlS[HIDDEN * WLD];   // 34.8 KB
    __shared__ unsigned short zS[128 * ZLD];       // 34.8 KB, row-major z tile

    int t = threadIdx.x;
    {   // stage W1 hi/lo
        const short8* gh = (const short8*)W1h;
        const short8* gl = (const short8*)W1l;
        #pragma unroll
        for (int i = 0; i < 8; ++i) {
            int idx = i * 256 + t;
            int row = idx >> 4, kk = (idx & 15) * 8;
            *(short8*)(WhS + row * WLD + kk) = gh[idx];
            *(short8*)(WlS + row * WLD + kk) = gl[idx];
        }
    }
    __syncthreads();

    int w = t >> 6, l = t & 63;
    int lane16 = l & 15, quad = l >> 4;
    int node_base = blockIdx.x * 128;

    // ---- phase 1: z^T tiles; wave w owns z-col subtiles {2w,2w+1} x 8 node subtiles
    floatx4 acc[2][8];
    #pragma unroll
    for (int m = 0; m < 2; ++m)
        #pragma unroll
        for (int nt = 0; nt < 8; ++nt) acc[m][nt] = (floatx4){0.f, 0.f, 0.f, 0.f};

    #pragma unroll
    for (int kc = 0; kc < 4; ++kc) {
        int k0 = kc * 32 + quad * 8;
        short8 bt[8];                                 // B-frags: T rows (global)
        #pragma unroll
        for (int nt = 0; nt < 8; ++nt) {
            int r = node_base + nt * 16 + lane16;
            if (r < N_NODES) bt[nt] = *(const short8*)(Ab + (size_t)r * HIDDEN + k0);
            else             bt[nt] = (short8){0,0,0,0,0,0,0,0};
        }
        short8 awh[2], awl[2];                        // A-frags: W1T rows (LDS)
        #pragma unroll
        for (int m = 0; m < 2; ++m) {
            int zc = (2 * w + m) * 16 + lane16;
            awh[m] = *(const short8*)(WhS + zc * WLD + k0);
            awl[m] = *(const short8*)(WlS + zc * WLD + k0);
        }
        #pragma unroll
        for (int m = 0; m < 2; ++m)
            #pragma unroll
            for (int nt = 0; nt < 8; ++nt) {
                acc[m][nt] = __builtin_amdgcn_mfma_f32_16x16x32_bf16(awh[m], bt[nt], acc[m][nt], 0, 0, 0);
                acc[m][nt] = __builtin_amdgcn_mfma_f32_16x16x32_bf16(awl[m], bt[nt], acc[m][nt], 0, 0, 0);
            }
    }
    // epilogue 1: bias + relu + rtne, 4 consecutive z-cols per lane -> b64 LDS store
    #pragma unroll
    for (int m = 0; m < 2; ++m) {
        int zc0 = (2 * w + m) * 16 + quad * 4;
        float4 bb = *(const float4*)(b1 + zc0);
        #pragma unroll
        for (int nt = 0; nt < 8; ++nt) {
            int node = nt * 16 + lane16;
            ushort4 pk;
            pk.x = bf16_rtne(fmaxf(acc[m][nt][0] + bb.x, 0.f));
            pk.y = bf16_rtne(fmaxf(acc[m][nt][1] + bb.y, 0.f));
            pk.z = bf16_rtne(fmaxf(acc[m][nt][2] + bb.z, 0.f));
            pk.w = bf16_rtne(fmaxf(acc[m][nt][3] + bb.w, 0.f));
            *(ushort4*)(zS + node * ZLD + zc0) = pk;
        }
    }
    __syncthreads();
    {   // stage W2 hi/lo over the same region
        const short8* gh = (const short8*)W2h;
        const short8* gl = (const short8*)W2l;
        #pragma unroll
        for (int i = 0; i < 8; ++i) {
            int idx = i * 256 + t;
            int row = idx >> 4, kk = (idx & 15) * 8;
            *(short8*)(WhS + row * WLD + kk) = gh[idx];
            *(short8*)(WlS + row * WLD + kk) = gl[idx];
        }
    }
    __syncthreads();

    // ---- phase 2: out = z @ W2 ; wave w owns node rows w*32..w*32+31
    floatx4 acc2[2][8];
    #pragma unroll
    for (int m = 0; m < 2; ++m)
        #pragma unroll
        for (int nt = 0; nt < 8; ++nt) acc2[m][nt] = (floatx4){0.f, 0.f, 0.f, 0.f};

    #pragma unroll
    for (int kc = 0; kc < 4; ++kc) {
        int k0 = kc * 32 + quad * 8;
        short8 az[2];                                 // A-frags: z rows (LDS b128)
        #pragma unroll
        for (int m = 0; m < 2; ++m) {
            int lr = w * 32 + m * 16 + lane16;
            az[m] = *(const short8*)(zS + lr * ZLD + k0);
        }
        short8 bh[8], bl8[8];                         // B-frags: W2T rows (LDS)
        #pragma unroll
        for (int nt = 0; nt < 8; ++nt) {
            int rr = nt * 16 + lane16;
            bh[nt]  = *(const short8*)(WhS + rr * WLD + k0);
            bl8[nt] = *(const short8*)(WlS + rr * WLD + k0);
        }
        #pragma unroll
        for (int m = 0; m < 2; ++m)
            #pragma unroll
            for (int nt = 0; nt < 8; ++nt) {
                acc2[m][nt] = __builtin_amdgcn_mfma_f32_16x16x32_bf16(az[m], bh[nt],  acc2[m][nt], 0, 0, 0);
                acc2[m][nt] = __builtin_amdgcn_mfma_f32_16x16x32_bf16(az[m], bl8[nt], acc2[m][nt], 0, 0, 0);
            }
    }
    // epilogue 2: C/D layout col=lane16, row=quad*4+reg
    #pragma unroll
    for (int nt = 0; nt < 8; ++nt) {
        int col = nt * 16 + lane16;
        float b = b2[col];
        #pragma unroll
        for (int m = 0; m < 2; ++m) {
            #pragma unroll
            for (int reg = 0; reg < 4; ++reg) {
                int r = node_base + w * 32 + m * 16 + quad * 4 + reg;
                if (r < N_NODES) {
                    float o = acc2[m][nt][reg] + b;
                    if (relu2) o = fmaxf(o, 0.f);
                    size_t oi = blocked
                        ? ((size_t)(col >> 5) * N_NODES + r) * 32 + (col & 31)
                        : (size_t)r * HIDDEN + col;
                    Cb[oi] = bf16_rtne(o);
                }
            }
        }
    }
}

// ---------------- fused pool + mean + linear head (reads bf16 h) ----------------
__global__ void pool_head_kernel(const unsigned short* __restrict__ H, const int* __restrict__ batch,
                                 const float* __restrict__ Wl, const float* __restrict__ bl,
                                 float* __restrict__ out) {
    int g = blockIdx.x;
    int t = threadIdx.x;   // 256 threads
    __shared__ int bounds[2];
    __shared__ float acc2[2 * HIDDEN];
    __shared__ float mean[HIDDEN];

    if (t < 2) {
        int target = g + t;
        int lo = 0, hi = N_NODES;
        while (lo < hi) {
            int mid = (lo + hi) >> 1;
            if (batch[mid] < target) lo = mid + 1; else hi = mid;
        }
        bounds[t] = lo;
    }
    __syncthreads();
    int r0 = bounds[0], r1 = bounds[1];

    int c = t & 127, half = t >> 7;
    float s = 0.f;
    for (int r = r0 + half; r < r1; r += 2)
        s += __uint_as_float((unsigned)H[(size_t)r * HIDDEN + c] << 16);
    acc2[half * HIDDEN + c] = s;
    __syncthreads();
    if (t < HIDDEN) {
        float cntf = (float)(r1 - r0);
        mean[t] = (acc2[t] + acc2[HIDDEN + t]) / fmaxf(cntf, 1.0f);
    }
    __syncthreads();
    if (t < N_CLASSES) {
        float o = bl[t];
        #pragma unroll 8
        for (int k = 0; k < HIDDEN; ++k) o = fmaf(mean[k], Wl[k * N_CLASSES + t], o);
        out[(size_t)g * N_CLASSES + t] = o;
    }
}

extern "C" void kernel_launch(void* const* d_in, const int* in_sizes, int n_in,
                              void* d_out, int out_size, void* d_ws, size_t ws_size,
                              hipStream_t stream) {
    const float* x   = (const float*)d_in[0];
    const int*   ei  = (const int*)d_in[1];       // [2][N_EDGES]: row0=src, row1=dst
    const int*   bat = (const int*)d_in[2];
    const float* W1  = (const float*)d_in[3];
    const float* b1  = (const float*)d_in[4];
    const float* W2  = (const float*)d_in[5];
    const float* b2  = (const float*)d_in[6];
    const float* Wl  = (const float*)d_in[7];
    const float* bl  = (const float*)d_in[8];
    float* out = (float*)d_out;

    const int* src = ei;
    const int* dst = ei + N_EDGES;

    char* w = (char*)d_ws;
    size_t off = 0;
    auto alloc = [&](size_t bytes) { void* p = w + off; off = (off + bytes + 255) & ~(size_t)255; return p; };
    unsigned short* g_bf  = (unsigned short*)alloc((size_t)N_NODES * HIDDEN * 2);  // gather table (XCD-blocked)
    unsigned short* t_bf  = (unsigned short*)alloc((size_t)N_NODES * HIDDEN * 2);  // agg out / final h (row-major)
    int*   deg     = (int*)  alloc((size_t)N_NODES * 4);
    int*   rowst   = (int*)  alloc((size_t)N_NODES * 4);
    int*   epos    = (int*)  alloc((size_t)N_EDGES * 4);
    int*   csr_src = (int*)  alloc((size_t)N_EDGES * 4);
    int*   counter = (int*)  alloc(256);
    unsigned short* w1h = (unsigned short*)alloc((size_t)HIDDEN * HIDDEN * 2);
    unsigned short* w1l = (unsigned short*)alloc((size_t)HIDDEN * HIDDEN * 2);
    unsigned short* w2h = (unsigned short*)alloc((size_t)HIDDEN * HIDDEN * 2);
    unsigned short* w2l = (unsigned short*)alloc((size_t)HIDDEN * HIDDEN * 2);
    (void)ws_size; (void)in_sizes; (void)n_in; (void)out_size;

    hipMemsetAsync(deg, 0, (size_t)N_NODES * 4, stream);

    // fused prep: count_pos | wsplit(+counter init) | xconv  (6378 blocks)
    prep_kernel<<<6378, 256, 0, stream>>>(dst, deg, epos, W1, w1h, w1l, W2, w2h, w2l,
                                          (const float4*)x, (uint4*)g_bf, counter);
    offsets_kernel<<<(N_NODES + 255) / 256, 256, 0, stream>>>(deg, rowst, counter);
    place_kernel<<<(N_EDGES + 255) / 256, 256, 0, stream>>>(src, dst, epos, rowst, csr_src);

    const int agg_grid = 4 * ((N_NODES + 63) / 64);  // 4 slices x 782 blocks
    const int mlp_grid = (N_NODES + 127) / 128;

    // layer 1
    agg_kernel<<<agg_grid, 256, 0, stream>>>((const uint4*)g_bf, rowst, deg, csr_src, (uint4*)t_bf);
    mlp_fused<<<mlp_grid, 256, 0, stream>>>(t_bf, w1h, w1l, b1, w2h, w2l, b2, g_bf, 1, 1);
    // layer 2
    agg_kernel<<<agg_grid, 256, 0, stream>>>((const uint4*)g_bf, rowst, deg, csr_src, (uint4*)t_bf);
    mlp_fused<<<mlp_grid, 256, 0, stream>>>(t_bf, w1h, w1l, b1, w2h, w2l, b2, g_bf, 1, 1);
    // layer 3 (no outer relu; row-major bf16 h into t_bf for pooling)
    agg_kernel<<<agg_grid, 256, 0, stream>>>((const uint4*)g_bf, rowst, deg, csr_src, (uint4*)t_bf);
    mlp_fused<<<mlp_grid, 256, 0, stream>>>(t_bf, w1h, w1l, b1, w2h, w2l, b2, t_bf, 0, 0);

    // fused mean-pool + head
    pool_head_kernel<<<N_GRAPHS, 256, 0, stream>>>(t_bf, bat, Wl, bl, out);
}

// Round 10
// 343.617 us; speedup vs baseline: 1.1107x; 1.1107x over previous
//
#include <hip/hip_runtime.h>

#define N_NODES  50000
#define N_EDGES  800000
#define HIDDEN   128
#define N_GRAPHS 256
#define N_CLASSES 10
#define WLD 136   // padded LDS leading dim for W tiles (4-bank shift/row -> 2-way max, free)

typedef short short8 __attribute__((ext_vector_type(8)));
typedef float floatx4 __attribute__((ext_vector_type(4)));

__device__ inline unsigned short bf16_rtne(float x) {
    unsigned u = __float_as_uint(x);
    unsigned r = ((u >> 16) & 1u) + 0x7fffu;
    return (unsigned short)((u + r) >> 16);
}

__device__ inline void bf16_split(float a, unsigned short& hi, unsigned short& lo) {
    unsigned u = __float_as_uint(a);
    hi = (unsigned short)(u >> 16);
    float res = a - __uint_as_float(u & 0xffff0000u);
    lo = (unsigned short)(__float_as_uint(res) >> 16);
}

// ---------------- fused prep: count_pos (blocks 0..3124) | wsplit (3125..3252) | xconv (3253..6377) ----------------
__global__ void prep_kernel(const int* __restrict__ dst, int* __restrict__ deg, int* __restrict__ epos,
                            const float* __restrict__ W1, unsigned short* __restrict__ W1h,
                            unsigned short* __restrict__ W1l,
                            const float* __restrict__ W2, unsigned short* __restrict__ W2h,
                            unsigned short* __restrict__ W2l,
                            const float4* __restrict__ X, uint4* __restrict__ Xb,
                            int* __restrict__ counter) {
    int b = blockIdx.x;
    if (b < 3125) {                              // count_pos: 3125*256 == 800000 exact
        int e = b * 256 + threadIdx.x;
        epos[e] = atomicAdd(&deg[dst[e]], 1);
    } else if (b < 3253) {                       // wsplit: 128*256 == 32768 exact
        int idx = (b - 3125) * 256 + threadIdx.x;
        if (idx == 0) counter[0] = 0;
        int which = idx >> 14, sub = idx & (HIDDEN * HIDDEN - 1);
        int k = sub >> 7, n = sub & 127;
        unsigned short hi, lo;
        bf16_split((which ? W2 : W1)[sub], hi, lo);
        (which ? W2h : W1h)[n * HIDDEN + k] = hi;
        (which ? W2l : W1l)[n * HIDDEN + k] = lo;
    } else {                                     // xconv: 3125*256 == 50000*16 exact
        int i = (b - 3253) * 256 + threadIdx.x;
        int n = i >> 4, c = i & 15;
        float4 a = X[(size_t)n * 32 + c * 2], v = X[(size_t)n * 32 + c * 2 + 1];
        uint4 o;
        o.x = (unsigned)bf16_rtne(a.x) | ((unsigned)bf16_rtne(a.y) << 16);
        o.y = (unsigned)bf16_rtne(a.z) | ((unsigned)bf16_rtne(a.w) << 16);
        o.z = (unsigned)bf16_rtne(v.x) | ((unsigned)bf16_rtne(v.y) << 16);
        o.w = (unsigned)bf16_rtne(v.z) | ((unsigned)bf16_rtne(v.w) << 16);
        Xb[(size_t)(c >> 2) * N_NODES * 4 + (size_t)n * 4 + (c & 3)] = o;
    }
}

__global__ void offsets_kernel(const int* __restrict__ deg, int* __restrict__ row_start,
                               int* __restrict__ counter) {
    int n = blockIdx.x * blockDim.x + threadIdx.x;
    int d = (n < N_NODES) ? deg[n] : 0;
    int lane = threadIdx.x & 63;
    int incl = d;
    #pragma unroll
    for (int off = 1; off < 64; off <<= 1) {
        int v = __shfl_up(incl, off, 64);
        if (lane >= off) incl += v;
    }
    int excl = incl - d;
    int total = __shfl(incl, 63, 64);
    int base = 0;
    if (lane == 0) base = atomicAdd(counter, total);
    base = __shfl(base, 0, 64);
    if (n < N_NODES) row_start[n] = base + excl;
}

__global__ void place_kernel(const int* __restrict__ src, const int* __restrict__ dst,
                             const int* __restrict__ epos, const int* __restrict__ row_start,
                             int* __restrict__ csr_src) {
    int e = blockIdx.x * blockDim.x + threadIdx.x;
    if (e >= N_EDGES) return;
    csr_src[row_start[dst[e]] + epos[e]] = src[e];
}

// ---------------- aggregation, XCD-sliced, sequential per-lane (R8-proven) ----------------
__device__ inline void acc_bf2(unsigned d, float& f0, float& f1) {
    f0 += __uint_as_float(d << 16);
    f1 += __uint_as_float(d & 0xffff0000u);
}
__device__ inline void acc8(const uint4 v, float* a) {
    acc_bf2(v.x, a[0], a[1]); acc_bf2(v.y, a[2], a[3]);
    acc_bf2(v.z, a[4], a[5]); acc_bf2(v.w, a[6], a[7]);
}

__global__ void agg_kernel(const uint4* __restrict__ Xb, const int* __restrict__ row_start,
                           const int* __restrict__ deg, const int* __restrict__ csr_src,
                           uint4* __restrict__ Tb /* row-major bf16 out */) {
    int s = blockIdx.x & 3;
    int n = (blockIdx.x >> 2) * 64 + (threadIdx.x >> 2);
    int chunk = threadIdx.x & 3;
    if (n >= N_NODES) return;
    const uint4* Ts = Xb + (size_t)s * (N_NODES * 4);
    float a[8];
    #pragma unroll
    for (int j = 0; j < 8; ++j) a[j] = 0.f;
    {   // self term
        uint4 v = Ts[(size_t)n * 4 + chunk];
        acc8(v, a);
    }
    int rs = row_start[n], d = deg[n];
    int i = 0;
    for (; i + 4 <= d; i += 4) {
        int s0 = csr_src[rs + i + 0];
        int s1 = csr_src[rs + i + 1];
        int s2 = csr_src[rs + i + 2];
        int s3 = csr_src[rs + i + 3];
        uint4 v0 = Ts[(size_t)s0 * 4 + chunk];
        uint4 v1 = Ts[(size_t)s1 * 4 + chunk];
        uint4 v2 = Ts[(size_t)s2 * 4 + chunk];
        uint4 v3 = Ts[(size_t)s3 * 4 + chunk];
        acc8(v0, a); acc8(v1, a); acc8(v2, a); acc8(v3, a);
    }
    for (; i < d; ++i) {
        int s0 = csr_src[rs + i];
        uint4 v0 = Ts[(size_t)s0 * 4 + chunk];
        acc8(v0, a);
    }
    uint4 o;
    o.x = (unsigned)bf16_rtne(a[0]) | ((unsigned)bf16_rtne(a[1]) << 16);
    o.y = (unsigned)bf16_rtne(a[2]) | ((unsigned)bf16_rtne(a[3]) << 16);
    o.z = (unsigned)bf16_rtne(a[4]) | ((unsigned)bf16_rtne(a[5]) << 16);
    o.w = (unsigned)bf16_rtne(a[6]) | ((unsigned)bf16_rtne(a[7]) << 16);
    Tb[(size_t)n * 16 + s * 4 + chunk] = o;
}

// ---------------- MFMA matmul, N-split: out = act(A @ W + b), 64 cols per block ----------------
// blockIdx.y selects col half; W hi/lo for those 64 cols staged in LDS (34.8 KB -> 4 blocks/CU).
// A: single bf16 row-major. Numerics identical to the 128-col version.
__global__ __launch_bounds__(256)
void mm_mfma(const unsigned short* __restrict__ Ab,
             const unsigned short* __restrict__ Bh, const unsigned short* __restrict__ Bl,
             const float* __restrict__ bias,
             unsigned short* __restrict__ Cb, int relu, int blocked) {
    __shared__ unsigned short WhS[64 * WLD];   // 17.4 KB
    __shared__ unsigned short WlS[64 * WLD];   // 17.4 KB

    int t = threadIdx.x;
    int col_base = blockIdx.y * 64;
    {   // stage W hi/lo for 64 cols: 1024 ushort8 each, 4 per thread
        const short8* gh = (const short8*)(Bh + (size_t)col_base * HIDDEN);
        const short8* gl = (const short8*)(Bl + (size_t)col_base * HIDDEN);
        #pragma unroll
        for (int i = 0; i < 4; ++i) {
            int idx = i * 256 + t;              // 0..1023
            int row = idx >> 4, kk = (idx & 15) * 8;
            *(short8*)(WhS + row * WLD + kk) = gh[idx];
            *(short8*)(WlS + row * WLD + kk) = gl[idx];
        }
    }
    __syncthreads();

    int w = t >> 6;
    int l = t & 63;
    int lane16 = l & 15;
    int quad = l >> 4;
    int row_base = blockIdx.x * 128 + w * 32;

    floatx4 acc[2][4];
    #pragma unroll
    for (int m = 0; m < 2; ++m)
        #pragma unroll
        for (int nt = 0; nt < 4; ++nt) acc[m][nt] = (floatx4){0.f, 0.f, 0.f, 0.f};

    #pragma unroll
    for (int kc = 0; kc < 4; ++kc) {
        int k0 = kc * 32 + quad * 8;
        short8 af[2];
        #pragma unroll
        for (int m = 0; m < 2; ++m) {
            int r = row_base + m * 16 + lane16;
            if (r < N_NODES) af[m] = *(const short8*)(Ab + (size_t)r * HIDDEN + k0);
            else             af[m] = (short8){0,0,0,0,0,0,0,0};
        }
        short8 bh[4], bl8[4];
        #pragma unroll
        for (int nt = 0; nt < 4; ++nt) {
            bh[nt]  = *(const short8*)(WhS + (nt * 16 + lane16) * WLD + k0);
            bl8[nt] = *(const short8*)(WlS + (nt * 16 + lane16) * WLD + k0);
        }
        #pragma unroll
        for (int m = 0; m < 2; ++m)
            #pragma unroll
            for (int nt = 0; nt < 4; ++nt) {
                acc[m][nt] = __builtin_amdgcn_mfma_f32_16x16x32_bf16(af[m], bh[nt],  acc[m][nt], 0, 0, 0);
                acc[m][nt] = __builtin_amdgcn_mfma_f32_16x16x32_bf16(af[m], bl8[nt], acc[m][nt], 0, 0, 0);
            }
    }
    // epilogue: C/D layout col=lane16, row=quad*4+reg
    #pragma unroll
    for (int nt = 0; nt < 4; ++nt) {
        int col = col_base + nt * 16 + lane16;
        float b = bias[col];
        #pragma unroll
        for (int m = 0; m < 2; ++m) {
            #pragma unroll
            for (int reg = 0; reg < 4; ++reg) {
                int r = row_base + m * 16 + quad * 4 + reg;
                if (r < N_NODES) {
                    float o = acc[m][nt][reg] + b;
                    if (relu) o = fmaxf(o, 0.f);
                    size_t oi = blocked
                        ? ((size_t)(col >> 5) * N_NODES + r) * 32 + (col & 31)
                        : (size_t)r * HIDDEN + col;
                    Cb[oi] = bf16_rtne(o);
                }
            }
        }
    }
}

// ---------------- fused pool + mean + linear head (reads bf16 h) ----------------
__global__ void pool_head_kernel(const unsigned short* __restrict__ H, const int* __restrict__ batch,
                                 const float* __restrict__ Wl, const float* __restrict__ bl,
                                 float* __restrict__ out) {
    int g = blockIdx.x;
    int t = threadIdx.x;   // 256 threads
    __shared__ int bounds[2];
    __shared__ float acc2[2 * HIDDEN];
    __shared__ float mean[HIDDEN];

    if (t < 2) {
        int target = g + t;
        int lo = 0, hi = N_NODES;
        while (lo < hi) {
            int mid = (lo + hi) >> 1;
            if (batch[mid] < target) lo = mid + 1; else hi = mid;
        }
        bounds[t] = lo;
    }
    __syncthreads();
    int r0 = bounds[0], r1 = bounds[1];

    int c = t & 127, half = t >> 7;
    float s = 0.f;
    for (int r = r0 + half; r < r1; r += 2)
        s += __uint_as_float((unsigned)H[(size_t)r * HIDDEN + c] << 16);
    acc2[half * HIDDEN + c] = s;
    __syncthreads();
    if (t < HIDDEN) {
        float cntf = (float)(r1 - r0);
        mean[t] = (acc2[t] + acc2[HIDDEN + t]) / fmaxf(cntf, 1.0f);
    }
    __syncthreads();
    if (t < N_CLASSES) {
        float o = bl[t];
        #pragma unroll 8
        for (int k = 0; k < HIDDEN; ++k) o = fmaf(mean[k], Wl[k * N_CLASSES + t], o);
        out[(size_t)g * N_CLASSES + t] = o;
    }
}

extern "C" void kernel_launch(void* const* d_in, const int* in_sizes, int n_in,
                              void* d_out, int out_size, void* d_ws, size_t ws_size,
                              hipStream_t stream) {
    const float* x   = (const float*)d_in[0];
    const int*   ei  = (const int*)d_in[1];       // [2][N_EDGES]: row0=src, row1=dst
    const int*   bat = (const int*)d_in[2];
    const float* W1  = (const float*)d_in[3];
    const float* b1  = (const float*)d_in[4];
    const float* W2  = (const float*)d_in[5];
    const float* b2  = (const float*)d_in[6];
    const float* Wl  = (const float*)d_in[7];
    const float* bl  = (const float*)d_in[8];
    float* out = (float*)d_out;

    const int* src = ei;
    const int* dst = ei + N_EDGES;

    char* w = (char*)d_ws;
    size_t off = 0;
    auto alloc = [&](size_t bytes) { void* p = w + off; off = (off + bytes + 255) & ~(size_t)255; return p; };
    unsigned short* g_bf  = (unsigned short*)alloc((size_t)N_NODES * HIDDEN * 2);  // gather table (XCD-blocked)
    unsigned short* t_bf  = (unsigned short*)alloc((size_t)N_NODES * HIDDEN * 2);  // agg out / final h (row-major)
    unsigned short* z_bf  = (unsigned short*)alloc((size_t)N_NODES * HIDDEN * 2);  // mm1 out (row-major)
    int*   deg     = (int*)  alloc((size_t)N_NODES * 4);
    int*   rowst   = (int*)  alloc((size_t)N_NODES * 4);
    int*   epos    = (int*)  alloc((size_t)N_EDGES * 4);
    int*   csr_src = (int*)  alloc((size_t)N_EDGES * 4);
    int*   counter = (int*)  alloc(256);
    unsigned short* w1h = (unsigned short*)alloc((size_t)HIDDEN * HIDDEN * 2);
    unsigned short* w1l = (unsigned short*)alloc((size_t)HIDDEN * HIDDEN * 2);
    unsigned short* w2h = (unsigned short*)alloc((size_t)HIDDEN * HIDDEN * 2);
    unsigned short* w2l = (unsigned short*)alloc((size_t)HIDDEN * HIDDEN * 2);
    (void)ws_size; (void)in_sizes; (void)n_in; (void)out_size;

    hipMemsetAsync(deg, 0, (size_t)N_NODES * 4, stream);

    // fused prep: count_pos | wsplit(+counter init) | xconv  (6378 blocks)
    prep_kernel<<<6378, 256, 0, stream>>>(dst, deg, epos, W1, w1h, w1l, W2, w2h, w2l,
                                          (const float4*)x, (uint4*)g_bf, counter);
    offsets_kernel<<<(N_NODES + 255) / 256, 256, 0, stream>>>(deg, rowst, counter);
    place_kernel<<<(N_EDGES + 255) / 256, 256, 0, stream>>>(src, dst, epos, rowst, csr_src);

    const int agg_grid = 4 * ((N_NODES + 63) / 64);      // 4 slices x 782 blocks
    const dim3 mm_grid((N_NODES + 127) / 128, 2);        // 391 x 2 col-halves

    // layer 1
    agg_kernel<<<agg_grid, 256, 0, stream>>>((const uint4*)g_bf, rowst, deg, csr_src, (uint4*)t_bf);
    mm_mfma<<<mm_grid, 256, 0, stream>>>(t_bf, w1h, w1l, b1, z_bf, 1, 0);
    mm_mfma<<<mm_grid, 256, 0, stream>>>(z_bf, w2h, w2l, b2, g_bf, 1, 1);
    // layer 2
    agg_kernel<<<agg_grid, 256, 0, stream>>>((const uint4*)g_bf, rowst, deg, csr_src, (uint4*)t_bf);
    mm_mfma<<<mm_grid, 256, 0, stream>>>(t_bf, w1h, w1l, b1, z_bf, 1, 0);
    mm_mfma<<<mm_grid, 256, 0, stream>>>(z_bf, w2h, w2l, b2, g_bf, 1, 1);
    // layer 3 (no outer relu; row-major bf16 h into t_bf for pooling)
    agg_kernel<<<agg_grid, 256, 0, stream>>>((const uint4*)g_bf, rowst, deg, csr_src, (uint4*)t_bf);
    mm_mfma<<<mm_grid, 256, 0, stream>>>(t_bf, w1h, w1l, b1, z_bf, 1, 0);
    mm_mfma<<<mm_grid, 256, 0, stream>>>(z_bf, w2h, w2l, b2, t_bf, 0, 0);

    // fused mean-pool + head
    pool_head_kernel<<<N_GRAPHS, 256, 0, stream>>>(t_bf, bat, Wl, bl, out);
}